// Round 9
// baseline (250.270 us; speedup 1.0000x reference)
//
#include <hip/hip_runtime.h>
#include <cstdint>

#define BB 4
#define NN 4096
#define CCH 256

typedef __attribute__((ext_vector_type(8))) short bf16x8;
typedef __attribute__((ext_vector_type(4))) float f32x4;

__device__ __forceinline__ unsigned short bf16rn(float f){
  unsigned u = __float_as_uint(f);
  unsigned r = u + 0x7FFFu + ((u>>16)&1u);
  return (unsigned short)(r>>16);
}
__device__ __forceinline__ float bf16tof(unsigned short h){
  return __uint_as_float(((unsigned)h)<<16);
}
__device__ __forceinline__ void gl_lds16(const void* g, void* l){
  __builtin_amdgcn_global_load_lds(
    (const __attribute__((address_space(1))) void*)g,
    (__attribute__((address_space(3))) void*)l, 16, 0, 0);
}

__device__ __forceinline__ float wredSum(float v){
#pragma unroll
  for (int o=32;o;o>>=1) v += __shfl_down(v,o);
  return v;
}
__device__ __forceinline__ float wredMax(float v){
#pragma unroll
  for (int o=32;o;o>>=1) v = fmaxf(v,__shfl_down(v,o));
  return v;
}
__device__ __forceinline__ int wredSumI(int v){
#pragma unroll
  for (int o=32;o;o>>=1) v += __shfl_down(v,o);
  return v;
}

// ---- prep: split x -> xs [16384][768] bf16 (hi | lo | hi) ----
__global__ __launch_bounds__(256) void prep_x(
    const float* __restrict__ x, unsigned short* __restrict__ xs)
{
  const int stride = gridDim.x * 256;
  for (int idx = blockIdx.x*256 + threadIdx.x; idx < 16384*64; idx += stride){
    const int r = idx >> 6, c4 = (idx & 63) * 4;
    float4 u = *(const float4*)(x + (size_t)r*256 + c4);
    ushort4 h, l;
    h.x=bf16rn(u.x); l.x=bf16rn(u.x - bf16tof(h.x));
    h.y=bf16rn(u.y); l.y=bf16rn(u.y - bf16tof(h.y));
    h.z=bf16rn(u.z); l.z=bf16rn(u.z - bf16tof(h.z));
    h.w=bf16rn(u.w); l.w=bf16rn(u.w - bf16tof(h.w));
    unsigned short* row = xs + (size_t)r*768;
    *(ushort4*)(row + c4)       = h;
    *(ushort4*)(row + 256 + c4) = l;
    *(ushort4*)(row + 512 + c4) = h;
  }
}

// ---- prep: weights -> Wt [512][768] bf16 (hi | hi | lo), rows = output cols ----
__global__ __launch_bounds__(256) void prep_w(
    const float* __restrict__ W1, const float* __restrict__ W2,
    const float* __restrict__ Wa, unsigned short* __restrict__ Wt)
{
  const int n = blockIdx.x;      // 512
  const int k = threadIdx.x;     // 256
  float w = (n < 128) ? W1[(size_t)k*128 + n]
          : (n < 256) ? W2[(size_t)k*128 + (n-128)]
                      : Wa[(size_t)k*256 + (n-256)];
  unsigned short h = bf16rn(w);
  unsigned short l = bf16rn(w - bf16tof(h));
  unsigned short* row = Wt + (size_t)n*768;
  row[k] = h; row[256+k] = h; row[512+k] = l;
}

// stage A(64 rows) + B(128 rows) 64-wide bf16 K-slice into LDS buffers
__device__ __forceinline__ void stage64_128(
    const unsigned short* __restrict__ ap, const unsigned short* __restrict__ bp,
    int strideA, int strideB, int kk, short* As, short* Bs, int r32, int seg)
{
#pragma unroll
  for (int i=0;i<2;i++){
    const int rowL = r32 + i*32;
    const int sw = (seg ^ (rowL & 7)) * 8;
    gl_lds16(ap + (size_t)rowL*strideA + kk + sw, &As[rowL*64 + seg*8]);
  }
#pragma unroll
  for (int i=0;i<4;i++){
    const int rowL = r32 + i*32;
    const int sw = (seg ^ (rowL & 7)) * 8;
    gl_lds16(bp + (size_t)rowL*strideB + kk + sw, &Bs[rowL*64 + seg*8]);
  }
}

// compute one 64-K-slice: acc[2][4] += A(32x64 per wave-row) x B^T
__device__ __forceinline__ void compute64_128(
    const short* As, const short* Bs, int wr, int wc, int fr, int fq,
    f32x4 (&acc)[2][4])
{
  bf16x8 af[2][2], bf[4][2];
#pragma unroll
  for (int m=0;m<2;m++){
    const int ar_ = wr*32 + m*16 + fr;
#pragma unroll
    for (int ks=0;ks<2;ks++)
      af[m][ks] = *(const bf16x8*)&As[ar_*64 + (((ks*4+fq) ^ (ar_&7))*8)];
  }
#pragma unroll
  for (int n=0;n<4;n++){
    const int br_ = wc*64 + n*16 + fr;
#pragma unroll
    for (int ks=0;ks<2;ks++)
      bf[n][ks] = *(const bf16x8*)&Bs[br_*64 + (((ks*4+fq) ^ (br_&7))*8)];
  }
#pragma unroll
  for (int m=0;m<2;m++)
#pragma unroll
    for (int n=0;n<4;n++)
#pragma unroll
      for (int ks=0;ks<2;ks++)
        acc[m][n] = __builtin_amdgcn_mfma_f32_16x16x32_bf16(af[m][ks], bf[n][ks], acc[m][n], 0,0,0);
}

// ---- fused projection GEMM: 64x128 tile, K=768, 2-phase issue-early dbuf ----
__global__ __launch_bounds__(256) void proj_mfma(
    const unsigned short* __restrict__ xs, const unsigned short* __restrict__ Wt,
    const float* __restrict__ b1, const float* __restrict__ a1,
    const float* __restrict__ b2, const float* __restrict__ a2,
    const float* __restrict__ ba, const float* __restrict__ aa,
    unsigned short* __restrict__ e1x, unsigned short* __restrict__ e2x,
    float* __restrict__ Vf)
{
  __shared__ __align__(16) short As[2][64*64];
  __shared__ __align__(16) short Bs[2][128*64];
  const int t = threadIdx.x;
  const int m0 = blockIdx.y*64, n0 = blockIdx.x*128;
  const int wid = t>>6, lane = t&63;
  const int wr = wid>>1, wc = wid&1;
  const int fr = lane&15, fq = lane>>4;
  const int r32 = t>>3, seg = t&7;

  const unsigned short* ap = xs + (size_t)m0*768;
  const unsigned short* bp = Wt + (size_t)n0*768;

  f32x4 acc[2][4];
#pragma unroll
  for (int m=0;m<2;m++)
#pragma unroll
    for (int n=0;n<4;n++) acc[m][n] = (f32x4){0.f,0.f,0.f,0.f};

  stage64_128(ap, bp, 768, 768, 0, As[0], Bs[0], r32, seg);
  __syncthreads();
  int cur = 0;
#pragma unroll
  for (int s=0;s<12;s++){
    if (s < 11)
      stage64_128(ap, bp, 768, 768, (s+1)*64, As[cur^1], Bs[cur^1], r32, seg);
    compute64_128(As[cur], Bs[cur], wr, wc, fr, fq, acc);
    __syncthreads();          // drains vmcnt: next buffer staged & all reads done
    cur ^= 1;
  }

  const int bx = blockIdx.x;
  if (bx < 2){
    const float* bb = bx ? b2 : b1;
    const float al = bx ? a2[0] : a1[0];
    unsigned short* ex = bx ? e2x : e1x;
#pragma unroll
    for (int m=0;m<2;m++){
#pragma unroll
      for (int n=0;n<4;n++){
        const int c = wc*64 + n*16 + fr;
        const float bias = bb[c];
#pragma unroll
        for (int reg=0;reg<4;reg++){
          const size_t r = (size_t)(m0 + wr*32 + m*16 + fq*4 + reg);
          float u = acc[m][n][reg] + bias;
          u = u >= 0.f ? u : al*u;
          unsigned short h = bf16rn(u);
          unsigned short l = bf16rn(u - bf16tof(h));
          if (bx == 0){            // e1x: [h | l | h]
            ex[r*384 + c] = h; ex[r*384 + 128 + c] = l; ex[r*384 + 256 + c] = h;
          } else {                 // e2x: [h | h | l]
            ex[r*384 + c] = h; ex[r*384 + 128 + c] = h; ex[r*384 + 256 + c] = l;
          }
        }
      }
    }
  } else {
    const float al = aa[0];
#pragma unroll
    for (int m=0;m<2;m++){
#pragma unroll
      for (int n=0;n<4;n++){
        const int c = (bx-2)*128 + wc*64 + n*16 + fr;
        const float bias = ba[c];
#pragma unroll
        for (int reg=0;reg<4;reg++){
          const size_t r = (size_t)(m0 + wr*32 + m*16 + fq*4 + reg);
          float u = acc[m][n][reg] + bias;
          Vf[r*CCH + c] = u >= 0.f ? u : al*u;
        }
      }
    }
  }
}

// ---- QK^T: 64x128 tile, K=384, 2-phase issue-early dbuf ----
__global__ __launch_bounds__(256) void qk_mfma(
    const unsigned short* __restrict__ e1, const unsigned short* __restrict__ e2,
    float* __restrict__ S)
{
  __shared__ __align__(16) short As[2][64*64];
  __shared__ __align__(16) short Bs[2][128*64];
  const int t = threadIdx.x;
  const int m0 = blockIdx.y*64, n0 = blockIdx.x*128;
  const int wid = t>>6, lane = t&63;
  const int wr = wid>>1, wc = wid&1;
  const int fr = lane&15, fq = lane>>4;
  const int r32 = t>>3, seg = t&7;

  const unsigned short* ap = e1 + (size_t)m0*384;
  const unsigned short* bp = e2 + (size_t)n0*384;

  f32x4 acc[2][4];
#pragma unroll
  for (int m=0;m<2;m++)
#pragma unroll
    for (int n=0;n<4;n++) acc[m][n] = (f32x4){0.f,0.f,0.f,0.f};

  stage64_128(ap, bp, 384, 384, 0, As[0], Bs[0], r32, seg);
  __syncthreads();
  int cur = 0;
#pragma unroll
  for (int s=0;s<6;s++){
    if (s < 5)
      stage64_128(ap, bp, 384, 384, (s+1)*64, As[cur^1], Bs[cur^1], r32, seg);
    compute64_128(As[cur], Bs[cur], wr, wc, fr, fq, acc);
    __syncthreads();
    cur ^= 1;
  }
#pragma unroll
  for (int m=0;m<2;m++){
#pragma unroll
    for (int n=0;n<4;n++){
#pragma unroll
      for (int reg=0;reg<4;reg++){
        const int r = m0 + wr*32 + m*16 + fq*4 + reg;
        const int c = n0 + wc*64 + n*16 + fr;
        S[(size_t)r*NN + c] = acc[m][n][reg];
      }
    }
  }
}

// ---- fused sparsemax + sparse PV ----
__global__ __launch_bounds__(256) void spv_kernel(
    const float* __restrict__ S, const float* __restrict__ V,
    const float* __restrict__ xr, float* __restrict__ out)
{
  const int row = blockIdx.x;
  const float4* sp = (const float4*)(S + (size_t)row * NN);
  const int t = threadIdx.x;
  const int lane = t & 63, wid = t >> 6;
  __shared__ float redf[4];
  __shared__ int   redi[4];
  __shared__ int   scan[256];
  __shared__ int   pidx[4096];
  __shared__ float pval[4096];

  float v[16];
  float mx = -1e30f;
#pragma unroll
  for (int j=0;j<4;j++){
    float4 u = sp[256*j + t];
    v[4*j]=u.x; v[4*j+1]=u.y; v[4*j+2]=u.z; v[4*j+3]=u.w;
    mx = fmaxf(mx, fmaxf(fmaxf(u.x,u.y), fmaxf(u.z,u.w)));
  }
  mx = wredMax(mx);
  if (lane==0) redf[wid] = mx;
  __syncthreads();
  mx = fmaxf(fmaxf(redf[0],redf[1]), fmaxf(redf[2],redf[3]));
  __syncthreads();
#pragma unroll
  for (int j=0;j<16;j++) v[j] -= mx;

  // Michelot fixed point from the filtered superset {v > -1} (tau >= max-1)
  float tau = -1.0f;
  int cnt = -1;
  for (int iter=0; iter<128; ++iter){
    float ps = 0.f; int pc = 0;
#pragma unroll
    for (int j=0;j<16;j++) if (v[j] > tau){ ps += v[j]; pc++; }
    ps = wredSum(ps); pc = wredSumI(pc);
    if (lane==0){ redf[wid] = ps; redi[wid] = pc; }
    __syncthreads();
    float S4 = redf[0]+redf[1]+redf[2]+redf[3];
    int   C4 = redi[0]+redi[1]+redi[2]+redi[3];
    __syncthreads();
    tau = (S4 - 1.f) / (float)C4;
    if (C4 == cnt) break;
    cnt = C4;
  }

  // deterministic nonzero extraction via block inclusive scan
  int lc = 0;
#pragma unroll
  for (int j=0;j<16;j++) if (v[j] > tau) lc++;
  scan[t] = lc;
  __syncthreads();
  for (int off=1; off<256; off<<=1){
    int xs_ = (t >= off) ? scan[t-off] : 0;
    __syncthreads();
    scan[t] += xs_;
    __syncthreads();
  }
  const int K = scan[255];
  int o = scan[t] - lc;
#pragma unroll
  for (int j=0;j<16;j++){
    if (v[j] > tau){
      pidx[o] = 1024*(j>>2) + 4*t + (j&3);
      pval[o] = v[j] - tau;
      o++;
    }
  }
  __syncthreads();

  float accv = xr[(size_t)row*CCH + t];
  for (int q=0;q<K;q++)
    accv = fmaf(pval[q], V[(size_t)pidx[q]*CCH + t], accv);
  out[(size_t)row*CCH + t] = accv;
}

extern "C" void kernel_launch(void* const* d_in, const int* in_sizes, int n_in,
                              void* d_out, int out_size, void* d_ws, size_t ws_size,
                              hipStream_t stream) {
  const float* x  = (const float*)d_in[0];
  const float* W1 = (const float*)d_in[1];
  const float* b1 = (const float*)d_in[2];
  const float* a1 = (const float*)d_in[3];
  const float* W2 = (const float*)d_in[4];
  const float* b2 = (const float*)d_in[5];
  const float* a2 = (const float*)d_in[6];
  const float* Wa = (const float*)d_in[7];
  const float* ba = (const float*)d_in[8];
  const float* aa = (const float*)d_in[9];
  float* out = (float*)d_out;

  // ws: xs 25.2MB | Wt 0.8MB | e1x 12.6MB | e2x 12.6MB | V 16.8MB | S 67MB
  unsigned short* xs  = (unsigned short*)d_ws;
  unsigned short* Wt  = xs  + (size_t)16384*768;
  unsigned short* e1x = Wt  + (size_t)512*768;
  unsigned short* e2x = e1x + (size_t)16384*384;
  float* Vf = (float*)(e2x + (size_t)16384*384);
  float* Sb = Vf + (size_t)BB*NN*CCH;

  dim3 blk(256);
  prep_x<<<dim3(2048,1,1), blk, 0, stream>>>(x, xs);
  prep_w<<<dim3(512,1,1), blk, 0, stream>>>(W1, W2, Wa, Wt);
  proj_mfma<<<dim3(4,256,1), blk, 0, stream>>>(xs, Wt, b1,a1, b2,a2, ba,aa,
                                               e1x, e2x, Vf);
  for (int b=0;b<BB;b++){
    const size_t co = (size_t)b*NN*CCH;
    qk_mfma<<<dim3(32,64,1), blk, 0, stream>>>(
        e1x + (size_t)b*NN*384, e2x + (size_t)b*NN*384, Sb);
    spv_kernel<<<dim3(NN,1,1), blk, 0, stream>>>(Sb, Vf + co, x + co, out + co);
  }
}

// Round 10
// 206.780 us; speedup vs baseline: 1.2103x; 1.2103x over previous
//
#include <hip/hip_runtime.h>
#include <cstdint>

#define BB 4
#define NN 4096
#define CCH 256

typedef __attribute__((ext_vector_type(8))) short bf16x8;
typedef __attribute__((ext_vector_type(4))) float f32x4;

__device__ __forceinline__ unsigned short bf16rn(float f){
  unsigned u = __float_as_uint(f);
  unsigned r = u + 0x7FFFu + ((u>>16)&1u);
  return (unsigned short)(r>>16);
}
__device__ __forceinline__ float bf16tof(unsigned short h){
  return __uint_as_float(((unsigned)h)<<16);
}
__device__ __forceinline__ void gl_lds16(const void* g, void* l){
  __builtin_amdgcn_global_load_lds(
    (const __attribute__((address_space(1))) void*)g,
    (__attribute__((address_space(3))) void*)l, 16, 0, 0);
}

__device__ __forceinline__ float wredSum(float v){
#pragma unroll
  for (int o=32;o;o>>=1) v += __shfl_down(v,o);
  return v;
}
__device__ __forceinline__ float wredMax(float v){
#pragma unroll
  for (int o=32;o;o>>=1) v = fmaxf(v,__shfl_down(v,o));
  return v;
}
__device__ __forceinline__ int wredSumI(int v){
#pragma unroll
  for (int o=32;o;o>>=1) v += __shfl_down(v,o);
  return v;
}

// ---- prep: split x -> xs [16384][768] bf16 (hi | lo | hi) ----
__global__ __launch_bounds__(256) void prep_x(
    const float* __restrict__ x, unsigned short* __restrict__ xs)
{
  const int stride = gridDim.x * 256;
  for (int idx = blockIdx.x*256 + threadIdx.x; idx < 16384*64; idx += stride){
    const int r = idx >> 6, c4 = (idx & 63) * 4;
    float4 u = *(const float4*)(x + (size_t)r*256 + c4);
    ushort4 h, l;
    h.x=bf16rn(u.x); l.x=bf16rn(u.x - bf16tof(h.x));
    h.y=bf16rn(u.y); l.y=bf16rn(u.y - bf16tof(h.y));
    h.z=bf16rn(u.z); l.z=bf16rn(u.z - bf16tof(h.z));
    h.w=bf16rn(u.w); l.w=bf16rn(u.w - bf16tof(h.w));
    unsigned short* row = xs + (size_t)r*768;
    *(ushort4*)(row + c4)       = h;
    *(ushort4*)(row + 256 + c4) = l;
    *(ushort4*)(row + 512 + c4) = h;
  }
}

// ---- prep: weights -> Wt [512][768] bf16 (hi | hi | lo), rows = output cols ----
__global__ __launch_bounds__(256) void prep_w(
    const float* __restrict__ W1, const float* __restrict__ W2,
    const float* __restrict__ Wa, unsigned short* __restrict__ Wt)
{
  const int n = blockIdx.x;      // 512
  const int k = threadIdx.x;     // 256
  float w = (n < 128) ? W1[(size_t)k*128 + n]
          : (n < 256) ? W2[(size_t)k*128 + (n-128)]
                      : Wa[(size_t)k*256 + (n-256)];
  unsigned short h = bf16rn(w);
  unsigned short l = bf16rn(w - bf16tof(h));
  unsigned short* row = Wt + (size_t)n*768;
  row[k] = h; row[256+k] = h; row[512+k] = l;
}

// ---- fused projection GEMM: 64x128 tile, K=768, single-buffer, XCD-swizzled ----
__global__ __launch_bounds__(256) void proj_mfma(
    const unsigned short* __restrict__ xs, const unsigned short* __restrict__ Wt,
    const float* __restrict__ b1, const float* __restrict__ a1,
    const float* __restrict__ b2, const float* __restrict__ a2,
    const float* __restrict__ ba, const float* __restrict__ aa,
    unsigned short* __restrict__ e1x, unsigned short* __restrict__ e2x,
    float* __restrict__ Vf)
{
  __shared__ __align__(16) short As[64*64];
  __shared__ __align__(16) short Bs[128*64];
  const int t = threadIdx.x;
  // XCD-aware swizzle: nwg=1024, 8 XCDs, 128 blocks/XCD.
  // W is by-major (W = by*4+bx): each XCD gets 32 consecutive by x all 4 bx
  // -> per-XCD working set = A 32x98KB(L2-resident via reuse) + B 4x197KB ~ 3.9MB
  {
  }
  const int bid = blockIdx.y * 4 + blockIdx.x;
  const int W = (bid & 7) * 128 + (bid >> 3);
  const int bx = W & 3, by = W >> 2;
  const int m0 = by*64, n0 = bx*128;
  const int wid = t>>6, lane = t&63;
  const int wr = wid>>1, wc = wid&1;
  const int fr = lane&15, fq = lane>>4;
  const int r32 = t>>3, seg = t&7;

  const unsigned short* ap = xs + (size_t)m0*768;
  const unsigned short* bp = Wt + (size_t)n0*768;

  f32x4 acc[2][4];
#pragma unroll
  for (int m=0;m<2;m++)
#pragma unroll
    for (int n=0;n<4;n++) acc[m][n] = (f32x4){0.f,0.f,0.f,0.f};

#pragma unroll
  for (int s=0;s<12;s++){
    const int kk = s*64;
#pragma unroll
    for (int i=0;i<2;i++){
      const int rowL = r32 + i*32;
      const int sw = (seg ^ (rowL & 7)) * 8;
      gl_lds16(ap + (size_t)rowL*768 + kk + sw, &As[rowL*64 + seg*8]);
    }
#pragma unroll
    for (int i=0;i<4;i++){
      const int rowL = r32 + i*32;
      const int sw = (seg ^ (rowL & 7)) * 8;
      gl_lds16(bp + (size_t)rowL*768 + kk + sw, &Bs[rowL*64 + seg*8]);
    }
    __syncthreads();
    bf16x8 af[2][2], bf[4][2];
#pragma unroll
    for (int m=0;m<2;m++){
      const int ar_ = wr*32 + m*16 + fr;
#pragma unroll
      for (int ks=0;ks<2;ks++)
        af[m][ks] = *(const bf16x8*)&As[ar_*64 + (((ks*4+fq) ^ (ar_&7))*8)];
    }
#pragma unroll
    for (int n=0;n<4;n++){
      const int br_ = wc*64 + n*16 + fr;
#pragma unroll
      for (int ks=0;ks<2;ks++)
        bf[n][ks] = *(const bf16x8*)&Bs[br_*64 + (((ks*4+fq) ^ (br_&7))*8)];
    }
#pragma unroll
    for (int m=0;m<2;m++)
#pragma unroll
      for (int n=0;n<4;n++)
#pragma unroll
        for (int ks=0;ks<2;ks++)
          acc[m][n] = __builtin_amdgcn_mfma_f32_16x16x32_bf16(af[m][ks], bf[n][ks], acc[m][n], 0,0,0);
    __syncthreads();
  }

  if (bx < 2){
    const float* bb = bx ? b2 : b1;
    const float al = bx ? a2[0] : a1[0];
    unsigned short* ex = bx ? e2x : e1x;
#pragma unroll
    for (int m=0;m<2;m++){
#pragma unroll
      for (int n=0;n<4;n++){
        const int c = wc*64 + n*16 + fr;
        const float bias = bb[c];
#pragma unroll
        for (int reg=0;reg<4;reg++){
          const size_t r = (size_t)(m0 + wr*32 + m*16 + fq*4 + reg);
          float u = acc[m][n][reg] + bias;
          u = u >= 0.f ? u : al*u;
          unsigned short h = bf16rn(u);
          unsigned short l = bf16rn(u - bf16tof(h));
          if (bx == 0){            // e1x: [h | l | h]
            ex[r*384 + c] = h; ex[r*384 + 128 + c] = l; ex[r*384 + 256 + c] = h;
          } else {                 // e2x: [h | h | l]
            ex[r*384 + c] = h; ex[r*384 + 128 + c] = h; ex[r*384 + 256 + c] = l;
          }
        }
      }
    }
  } else {
    const float al = aa[0];
#pragma unroll
    for (int m=0;m<2;m++){
#pragma unroll
      for (int n=0;n<4;n++){
        const int c = (bx-2)*128 + wc*64 + n*16 + fr;
        const float bias = ba[c];
#pragma unroll
        for (int reg=0;reg<4;reg++){
          const size_t r = (size_t)(m0 + wr*32 + m*16 + fq*4 + reg);
          float u = acc[m][n][reg] + bias;
          Vf[r*CCH + c] = u >= 0.f ? u : al*u;
        }
      }
    }
  }
}

// ---- QK^T: 128x128 tile, K=384, single-buffer, 2 batches/dispatch, XCD-swizzled ----
__global__ __launch_bounds__(256) void qk_mfma(
    const unsigned short* __restrict__ e1base, const unsigned short* __restrict__ e2base,
    float* __restrict__ Sbase)
{
  __shared__ __align__(16) short As[128*64];
  __shared__ __align__(16) short Bs[128*64];
  const int t = threadIdx.x;
  // nwg = 2048 (z=2, 32x32). W = (z*32+by)*32+bx; each XCD: 256 consecutive W
  // -> one z, 8 consecutive by, all bx: A 8x98KB + B 32x98KB ~ 3.9MB / XCD L2
  const int bid = (blockIdx.z * 32 + blockIdx.y) * 32 + blockIdx.x;
  const int W = (bid & 7) * 256 + (bid >> 3);
  const int bx = W & 31, by = (W >> 5) & 31, z = W >> 10;
  const int m0 = by*128, n0 = bx*128;
  const int wid = t>>6, lane = t&63;
  const int wr = wid>>1, wc = wid&1;
  const int fr = lane&15, fq = lane>>4;
  const int r32 = t>>3, seg = t&7;

  const unsigned short* ap = e1base + (size_t)z*NN*384 + (size_t)m0*384;
  const unsigned short* bp = e2base + (size_t)z*NN*384 + (size_t)n0*384;
  float* S = Sbase + (size_t)z*NN*NN;

  f32x4 acc[4][4];
#pragma unroll
  for (int m=0;m<4;m++)
#pragma unroll
    for (int n=0;n<4;n++) acc[m][n] = (f32x4){0.f,0.f,0.f,0.f};

#pragma unroll
  for (int s=0;s<6;s++){
    const int kk = s*64;
#pragma unroll
    for (int i=0;i<4;i++){
      const int rowL = r32 + i*32;
      const int sw = (seg ^ (rowL & 7)) * 8;
      gl_lds16(ap + (size_t)rowL*384 + kk + sw, &As[rowL*64 + seg*8]);
      gl_lds16(bp + (size_t)rowL*384 + kk + sw, &Bs[rowL*64 + seg*8]);
    }
    __syncthreads();
    bf16x8 af[4][2], bf[4][2];
#pragma unroll
    for (int m=0;m<4;m++){
      const int ar_ = wr*64 + m*16 + fr;
#pragma unroll
      for (int ks=0;ks<2;ks++)
        af[m][ks] = *(const bf16x8*)&As[ar_*64 + (((ks*4+fq) ^ (ar_&7))*8)];
    }
#pragma unroll
    for (int n=0;n<4;n++){
      const int br_ = wc*64 + n*16 + fr;
#pragma unroll
      for (int ks=0;ks<2;ks++)
        bf[n][ks] = *(const bf16x8*)&Bs[br_*64 + (((ks*4+fq) ^ (br_&7))*8)];
    }
#pragma unroll
    for (int m=0;m<4;m++)
#pragma unroll
      for (int n=0;n<4;n++)
#pragma unroll
        for (int ks=0;ks<2;ks++)
          acc[m][n] = __builtin_amdgcn_mfma_f32_16x16x32_bf16(af[m][ks], bf[n][ks], acc[m][n], 0,0,0);
    __syncthreads();
  }
#pragma unroll
  for (int m=0;m<4;m++){
#pragma unroll
    for (int n=0;n<4;n++){
#pragma unroll
      for (int reg=0;reg<4;reg++){
        const int r = m0 + wr*64 + m*16 + fq*4 + reg;
        const int c = n0 + wc*64 + n*16 + fr;
        S[(size_t)r*NN + c] = acc[m][n][reg];
      }
    }
  }
}

// ---- fused sparsemax + sparse PV; 2 batches/dispatch (b = row>>12) ----
__global__ __launch_bounds__(256) void spv_kernel(
    const float* __restrict__ S, const float* __restrict__ V,
    const float* __restrict__ xr, float* __restrict__ out)
{
  const int row = blockIdx.x;
  const int b = row >> 12;
  const float4* sp = (const float4*)(S + (size_t)row * NN);
  const int t = threadIdx.x;
  const int lane = t & 63, wid = t >> 6;
  __shared__ float redf[4];
  __shared__ int   redi[4];
  __shared__ int   scan[256];
  __shared__ int   pidx[4096];
  __shared__ float pval[4096];

  float v[16];
  float mx = -1e30f;
#pragma unroll
  for (int j=0;j<4;j++){
    float4 u = sp[256*j + t];
    v[4*j]=u.x; v[4*j+1]=u.y; v[4*j+2]=u.z; v[4*j+3]=u.w;
    mx = fmaxf(mx, fmaxf(fmaxf(u.x,u.y), fmaxf(u.z,u.w)));
  }
  mx = wredMax(mx);
  if (lane==0) redf[wid] = mx;
  __syncthreads();
  mx = fmaxf(fmaxf(redf[0],redf[1]), fmaxf(redf[2],redf[3]));
  __syncthreads();
#pragma unroll
  for (int j=0;j<16;j++) v[j] -= mx;

  // Michelot fixed point from the filtered superset {v > -1} (tau >= max-1)
  float tau = -1.0f;
  int cnt = -1;
  for (int iter=0; iter<128; ++iter){
    float ps = 0.f; int pc = 0;
#pragma unroll
    for (int j=0;j<16;j++) if (v[j] > tau){ ps += v[j]; pc++; }
    ps = wredSum(ps); pc = wredSumI(pc);
    if (lane==0){ redf[wid] = ps; redi[wid] = pc; }
    __syncthreads();
    float S4 = redf[0]+redf[1]+redf[2]+redf[3];
    int   C4 = redi[0]+redi[1]+redi[2]+redi[3];
    __syncthreads();
    tau = (S4 - 1.f) / (float)C4;
    if (C4 == cnt) break;
    cnt = C4;
  }

  // deterministic nonzero extraction via block inclusive scan
  int lc = 0;
#pragma unroll
  for (int j=0;j<16;j++) if (v[j] > tau) lc++;
  scan[t] = lc;
  __syncthreads();
  for (int off=1; off<256; off<<=1){
    int xs_ = (t >= off) ? scan[t-off] : 0;
    __syncthreads();
    scan[t] += xs_;
    __syncthreads();
  }
  const int K = scan[255];
  int o = scan[t] - lc;
#pragma unroll
  for (int j=0;j<16;j++){
    if (v[j] > tau){
      pidx[o] = 1024*(j>>2) + 4*t + (j&3);
      pval[o] = v[j] - tau;
      o++;
    }
  }
  __syncthreads();

  float accv = xr[(size_t)row*CCH + t];
  const float* Vb = V + ((size_t)b << 12) * CCH;
  for (int q=0;q<K;q++)
    accv = fmaf(pval[q], Vb[(size_t)pidx[q]*CCH + t], accv);
  out[(size_t)row*CCH + t] = accv;
}

extern "C" void kernel_launch(void* const* d_in, const int* in_sizes, int n_in,
                              void* d_out, int out_size, void* d_ws, size_t ws_size,
                              hipStream_t stream) {
  const float* x  = (const float*)d_in[0];
  const float* W1 = (const float*)d_in[1];
  const float* b1 = (const float*)d_in[2];
  const float* a1 = (const float*)d_in[3];
  const float* W2 = (const float*)d_in[4];
  const float* b2 = (const float*)d_in[5];
  const float* a2 = (const float*)d_in[6];
  const float* Wa = (const float*)d_in[7];
  const float* ba = (const float*)d_in[8];
  const float* aa = (const float*)d_in[9];
  float* out = (float*)d_out;

  // ws: xs 25.2MB | Wt 0.8MB | e1x 12.6MB | e2x 12.6MB | V 16.8MB | S2 134MB = 202MB
  unsigned short* xs  = (unsigned short*)d_ws;
  unsigned short* Wt  = xs  + (size_t)16384*768;
  unsigned short* e1x = Wt  + (size_t)512*768;
  unsigned short* e2x = e1x + (size_t)16384*384;
  float* Vf = (float*)(e2x + (size_t)16384*384);
  float* S2 = Vf + (size_t)BB*NN*CCH;

  dim3 blk(256);
  prep_x<<<dim3(2048,1,1), blk, 0, stream>>>(x, xs);
  prep_w<<<dim3(512,1,1), blk, 0, stream>>>(W1, W2, Wa, Wt);
  proj_mfma<<<dim3(4,256,1), blk, 0, stream>>>(xs, Wt, b1,a1, b2,a2, ba,aa,
                                               e1x, e2x, Vf);
  for (int pair=0;pair<2;pair++){
    const size_t eo = (size_t)pair*2*NN*384;
    const size_t co = (size_t)pair*2*NN*CCH;
    qk_mfma<<<dim3(32,32,2), blk, 0, stream>>>(e1x + eo, e2x + eo, S2);
    spv_kernel<<<dim3(2*NN,1,1), blk, 0, stream>>>(S2, Vf + co, x + co, out + co);
  }
}